// Round 8
// baseline (1503.235 us; speedup 1.0000x reference)
//
#include <hip/hip_runtime.h>

// Single persistent kernel: prep -> [hproj || fc_emb] -> energy -> [ctxsm ||
// fc_emb tail] -> [gates0 || fc_ctx] -> lstm0 -> gates1 -> lstm1 -> fc_h1+sum.
// 512 blocks x 256 threads, 64KB LDS -> exactly 2 blocks/CU co-resident.
// Grid barrier: agent-scope atomics + __threadfence (cross-XCD safe).

typedef __attribute__((ext_vector_type(8))) short bf16x8;
typedef __attribute__((ext_vector_type(4))) float f32x4;

#define NBLK 512

__device__ __forceinline__ short f2bf(float f){
  __bf16 h = (__bf16)f;
  return __builtin_bit_cast(short, h);
}
__device__ __forceinline__ bf16x8 cvt8(float4 a, float4 b){
  bf16x8 r;
  r[0]=f2bf(a.x); r[1]=f2bf(a.y); r[2]=f2bf(a.z); r[3]=f2bf(a.w);
  r[4]=f2bf(b.x); r[5]=f2bf(b.y); r[6]=f2bf(b.z); r[7]=f2bf(b.w);
  return r;
}
__device__ __forceinline__ bf16x8 ld8_bf(const float* __restrict__ p){
  return cvt8(*(const float4*)p, *(const float4*)(p + 4));
}
__device__ __forceinline__ float fast_tanh(float x){
  x = fminf(fmaxf(x, -15.f), 15.f);
  float t = __expf(2.f * x);
  return (t - 1.f) / (t + 1.f);
}
__device__ __forceinline__ float fast_sig(float x){
  return 1.f / (1.f + __expf(-x));
}
__device__ __forceinline__ void stage16(const void* src, void* dst_lds){
  __builtin_amdgcn_global_load_lds(
      (const __attribute__((address_space(1))) void*)src,
      (__attribute__((address_space(3))) void*)dst_lds, 16, 0, 0);
}

__device__ __forceinline__ void gridsync(unsigned* cnt, unsigned* gen){
  __threadfence();
  __syncthreads();
  if (threadIdx.x == 0){
    unsigned g = __hip_atomic_load(gen, __ATOMIC_RELAXED, __HIP_MEMORY_SCOPE_AGENT);
    unsigned a = __hip_atomic_fetch_add(cnt, 1u, __ATOMIC_ACQ_REL, __HIP_MEMORY_SCOPE_AGENT);
    if (a == NBLK - 1u){
      __hip_atomic_store(cnt, 0u, __ATOMIC_RELAXED, __HIP_MEMORY_SCOPE_AGENT);
      __hip_atomic_store(gen, g + 1u, __ATOMIC_RELEASE, __HIP_MEMORY_SCOPE_AGENT);
    } else {
      while (__hip_atomic_load(gen, __ATOMIC_ACQUIRE, __HIP_MEMORY_SCOPE_AGENT) == g)
        __builtin_amdgcn_s_sleep(2);
    }
  }
  __syncthreads();
  __threadfence();
}

// ---------------------------------------------------------------------------
// One 256-wide k-slice of C[64,64tile] += A_bf16[64,k0:k0+256] @ W[nb:nb+64,:]^T
// A staged to LDS (swizzled), W f32 via 2-buffer global_load_lds rotation.
// Wbase must already point at the k-slice column origin.
// ---------------------------------------------------------------------------
__device__ __forceinline__ void gemm_slice(
    short* Al, float* Wl,
    const short* A, int lda, int k0,
    const float* Wbase, int sW, int nb,
    f32x4 acc[4])
{
  const int wv   = threadIdx.x >> 6;
  const int lane = threadIdx.x & 63;
  const int l15  = lane & 15;
  const int lg   = lane >> 4;

  __builtin_amdgcn_s_barrier();          // protect Al/Wl reuse across slices
  #pragma unroll
  for (int i = 0; i < 8; ++i){           // stage A: 16 rows/wave, 2 rows/inst
    int rbase = wv*16 + i*2;
    int row   = rbase + (lane >> 5);
    const char* src = (const char*)A + (long)row*lda*2 + (long)k0*2
                      + (((lane & 31)*16) ^ ((row & 7) << 4));
    stage16(src, (void*)(Al + rbase*256));
  }
  // W stage: 16 rows/wave per 64-k buffer, 4 rows/inst
  #pragma unroll
  for (int i = 0; i < 4; ++i){
    int row = wv*16 + i*4 + lg;
    const char* src = (const char*)(Wbase + (long)(nb + row)*sW)
                      + ((l15*16) ^ ((row & 7) << 4));
    stage16(src, (void*)(Wl + (wv*16 + i*4)*64));
  }
  #pragma unroll
  for (int i = 0; i < 4; ++i){
    int row = wv*16 + i*4 + lg;
    const char* src = (const char*)(Wbase + (long)(nb + row)*sW + 64)
                      + ((l15*16) ^ ((row & 7) << 4));
    stage16(src, (void*)(Wl + 4096 + (wv*16 + i*4)*64));
  }
  asm volatile("s_waitcnt vmcnt(8)" ::: "memory");   // A done (W0,W1 in flight)
  __builtin_amdgcn_s_barrier();

  const int rl = wv*16 + l15;
  const int sw = (l15 & 7) << 4;
  const char* abase = (const char*)Al;

  #pragma unroll
  for (int t = 0; t < 4; ++t){
    if (t < 2){
      asm volatile("s_waitcnt vmcnt(4)" ::: "memory");
    } else if (t == 2){
      asm volatile("s_waitcnt vmcnt(4)" ::: "memory");
    } else {
      asm volatile("s_waitcnt vmcnt(0)" ::: "memory");
    }
    bf16x8 a[4][2];
    #pragma unroll
    for (int m = 0; m < 4; ++m)
      #pragma unroll
      for (int h = 0; h < 2; ++h){
        int cb = t*128 + h*64 + lg*16;
        a[m][h] = *(const bf16x8*)(abase + (m*16 + l15)*512 + (cb ^ sw));
      }
    const char* rb = (const char*)Wl + (t & 1)*16384 + rl*256;
    float4 w00 = *(const float4*)(rb + ((lg*32      ) ^ sw));
    float4 w01 = *(const float4*)(rb + ((lg*32 + 16 ) ^ sw));
    float4 w10 = *(const float4*)(rb + ((lg*32 + 128) ^ sw));
    float4 w11 = *(const float4*)(rb + ((lg*32 + 144) ^ sw));
    bf16x8 wf0 = cvt8(w00, w01);
    bf16x8 wf1 = cvt8(w10, w11);
    #pragma unroll
    for (int m = 0; m < 4; ++m)
      acc[m] = __builtin_amdgcn_mfma_f32_16x16x32_bf16(a[m][0], wf0, acc[m], 0,0,0);
    #pragma unroll
    for (int m = 0; m < 4; ++m)
      acc[m] = __builtin_amdgcn_mfma_f32_16x16x32_bf16(a[m][1], wf1, acc[m], 0,0,0);
    if (t < 2){   // stage next 64-k into the buffer just consumed
      #pragma unroll
      for (int i = 0; i < 4; ++i){
        int row = wv*16 + i*4 + lg;
        const char* src = (const char*)(Wbase + (long)(nb + row)*sW + (t+2)*64)
                          + ((l15*16) ^ ((row & 7) << 4));
        stage16(src, (void*)(Wl + (t & 1)*4096 + (wv*16 + i*4)*64));
      }
    }
  }
}

__device__ __forceinline__ void tile_store(float* dst, int N, int nb, f32x4 acc[4], int mode,
                                           const float* addsrc, const float* bias)
{
  const int lane = threadIdx.x & 63;
  const int wv   = threadIdx.x >> 6;
  const int l15  = lane & 15;
  const int lg   = lane >> 4;
  const int col  = nb + wv*16 + l15;
  float bn = (mode == 3) ? bias[col] : 0.f;
  #pragma unroll
  for (int mt = 0; mt < 4; ++mt)
    #pragma unroll
    for (int r = 0; r < 4; ++r){
      long idx = (long)(mt*16 + lg*4 + r) * N + col;
      float v = acc[mt][r];
      if (mode == 2) v += dst[idx];
      if (mode == 3) v += addsrc[idx] + bn;
      dst[idx] = v;
    }
}

// ---------------------------------------------------------------------------
__global__ __launch_bounds__(256, 2) void mega(
    const int* __restrict__ tok, const float* __restrict__ emb,
    const float* __restrict__ hidden, const float* __restrict__ cell,
    const float* __restrict__ enc, const int* __restrict__ mask,
    const float* __restrict__ attn_w, const float* __restrict__ attn_b,
    const float* __restrict__ v_w,
    const float* __restrict__ w_ih0, const float* __restrict__ w_hh0,
    const float* __restrict__ b_ih0, const float* __restrict__ b_hh0,
    const float* __restrict__ w_ih1, const float* __restrict__ w_hh1,
    const float* __restrict__ b_ih1, const float* __restrict__ b_hh1,
    const float* __restrict__ fc_w, const float* __restrict__ fc_b,
    short* encbf, short* Wbf, short* A0, short* A1, short* Zb,
    float* sco, float* PbH, float* predP, float* PbG, unsigned* bar,
    float* pred, float* nh, float* nc, float* aw)
{
  extern __shared__ char smem[];
  short* Al = (short*)smem;             // 32 KB
  float* Wl = (float*)(smem + 32768);   // 2 x 16 KB
  const int bid = blockIdx.x;
  const int t   = threadIdx.x;
  unsigned* cnt = bar;
  unsigned* gen = bar + 1;

  // ---------------- P0: prep (grid-stride) ----------------
  for (int vb = bid; vb < 4404; vb += NBLK){
    if (vb < 4096){
      long i = ((long)vb*256 + t)*8;
      *(bf16x8*)(encbf + i) = ld8_bf(enc + i);
    } else if (vb < 4352){
      int j = (vb-4096)*256 + t;
      int r = j >> 7, c = (j & 127)*8;
      *(bf16x8*)(Wbf + r*1024 + c) = ld8_bf(attn_w + (long)r*2048 + 1024 + c);
    } else if (vb < 4368){
      int j = (vb-4352)*256 + t;
      int b = j >> 6, e8 = (j & 63)*8;
      bf16x8 v = ld8_bf(emb + (long)tok[b]*512 + e8);
      *(bf16x8*)(A0 + b*2560 + e8) = v;
      *(bf16x8*)(Zb + b*2560 + 2048 + e8) = v;
    } else if (vb < 4400){
      int j = (vb-4368)*256 + t;
      int b = j >> 7, n8 = (j & 127)*8;
      *(bf16x8*)(A0 + b*2560 + 1536 + n8) = ld8_bf(hidden + (long)b*1024 + n8);
      *(bf16x8*)(A1 + b*2048 + 1024 + n8) = ld8_bf(hidden + 65536 + (long)b*1024 + n8);
    } else {
      int j = (vb-4400)*256 + t;
      float4 z = {0.f,0.f,0.f,0.f};
      *(float4*)(sco + j*8) = z;
      *(float4*)(sco + j*8 + 4) = z;
    }
  }
  gridsync(cnt, gen);

  // ---------------- P1: hproj (32 blks) || fc emb-segment (480 blks) -------
  if (bid < 32){
    f32x4 acc[4] = {};
    int ct = bid >> 2, sl = bid & 3;
    gemm_slice(Al, Wl, A1 + 1024, 2048, sl*256, attn_w + sl*256, 2048, ct*64, acc);
    tile_store(PbH + sl*32768, 512, ct*64, acc, 0, nullptr, nullptr);
  } else {
    int u = bid - 32;                 // 0..479
    f32x4 acc[4] = {};
    gemm_slice(Al, Wl, Zb, 2560, 2048, fc_w + 2048, 2560, u*64, acc);
    gemm_slice(Al, Wl, Zb, 2560, 2304, fc_w + 2304, 2560, u*64, acc);
    tile_store(predP, 32000, u*64, acc, 1, nullptr, nullptr);
  }
  gridsync(cnt, gen);

  // ---------------- P2: energy, 2 tiles/block ----------------
  #pragma unroll
  for (int e = 0; e < 2; ++e){
    const int vt = bid + e*512;
    const int m3 = vt & 127, n3 = vt >> 7;
    const int wave = t >> 6, lane = t & 63;
    const int l15 = lane & 15, lg = lane >> 4;
    const int mb = m3*64, nb = n3*64 + wave*16;
    const int b = mb >> 7;
    const int hi = b*512 + nb + l15;
    const float hp = attn_b[nb + l15] + PbH[hi] + PbH[32768 + hi]
                   + PbH[65536 + hi] + PbH[98304 + hi];
    f32x4 acc[4] = {};
    const short* ap  = encbf + (long)(mb + l15)*1024 + lg*8;
    const short* wpb = Wbf   + (long)(nb + l15)*1024 + lg*8;
    bf16x8 wn  = *(const bf16x8*)(wpb);
    bf16x8 an0 = *(const bf16x8*)(ap);
    bf16x8 an1 = *(const bf16x8*)(ap + 16*1024);
    bf16x8 an2 = *(const bf16x8*)(ap + 32*1024);
    bf16x8 an3 = *(const bf16x8*)(ap + 48*1024);
    for (int kb = 32; kb < 1024; kb += 32){
      bf16x8 wc = wn, c0 = an0, c1 = an1, c2 = an2, c3 = an3;
      wn  = *(const bf16x8*)(wpb + kb);
      an0 = *(const bf16x8*)(ap + kb);
      an1 = *(const bf16x8*)(ap + kb + 16*1024);
      an2 = *(const bf16x8*)(ap + kb + 32*1024);
      an3 = *(const bf16x8*)(ap + kb + 48*1024);
      acc[0] = __builtin_amdgcn_mfma_f32_16x16x32_bf16(c0, wc, acc[0], 0,0,0);
      acc[1] = __builtin_amdgcn_mfma_f32_16x16x32_bf16(c1, wc, acc[1], 0,0,0);
      acc[2] = __builtin_amdgcn_mfma_f32_16x16x32_bf16(c2, wc, acc[2], 0,0,0);
      acc[3] = __builtin_amdgcn_mfma_f32_16x16x32_bf16(c3, wc, acc[3], 0,0,0);
    }
    acc[0] = __builtin_amdgcn_mfma_f32_16x16x32_bf16(an0, wn, acc[0], 0,0,0);
    acc[1] = __builtin_amdgcn_mfma_f32_16x16x32_bf16(an1, wn, acc[1], 0,0,0);
    acc[2] = __builtin_amdgcn_mfma_f32_16x16x32_bf16(an2, wn, acc[2], 0,0,0);
    acc[3] = __builtin_amdgcn_mfma_f32_16x16x32_bf16(an3, wn, acc[3], 0,0,0);
    const float vn = v_w[nb + l15];
    #pragma unroll
    for (int mt = 0; mt < 4; ++mt){
      #pragma unroll
      for (int r = 0; r < 4; ++r){
        int m = mb + mt*16 + lg*4 + r;
        float ev = fast_tanh(acc[mt][r] + hp) * vn;
        ev += __shfl_xor(ev, 1, 16);
        ev += __shfl_xor(ev, 2, 16);
        ev += __shfl_xor(ev, 4, 16);
        ev += __shfl_xor(ev, 8, 16);
        if (l15 == 0) atomicAdd(&sco[m], ev);
      }
    }
  }
  gridsync(cnt, gen);

  // ---------------- P3: ctxsm (256) || fc emb tail (20) ----------------
  if (bid < 256){
    const int bb = bid & 63, dch = bid >> 6;
    float* red = (float*)smem;
    float* w   = red + 128;
    float v = 0.f;
    if (t < 128){
      v = sco[bb*128 + t];
      if (mask[bb*128 + t] == 0) v = -1e10f;
      red[t] = v;
    }
    __syncthreads();
    for (int d = 64; d > 0; d >>= 1){
      if (t < d) red[t] = fmaxf(red[t], red[t + d]);
      __syncthreads();
    }
    const float mx = red[0];
    __syncthreads();
    if (t < 128){ float e2 = __expf(v - mx); w[t] = e2; red[t] = e2; }
    __syncthreads();
    for (int d = 64; d > 0; d >>= 1){
      if (t < d) red[t] += red[t + d];
      __syncthreads();
    }
    const float inv = 1.f / red[0];
    if (dch == 0 && t < 128) aw[bb*128 + t] = w[t] * inv;
    const int dd = dch*256 + t;
    const unsigned short* e = (const unsigned short*)encbf + (long)bb*131072 + dd;
    float s = 0.f;
    #pragma unroll 4
    for (int si = 0; si < 128; ++si){
      float ev = __builtin_bit_cast(float, (unsigned)e[si*1024] << 16);
      s += w[si] * ev;
    }
    s *= inv;
    short vbf = f2bf(s);
    A0[bb*2560 + 512  + dd] = vbf;
    Zb[bb*2560 + 1024 + dd] = vbf;
  } else if (bid < 276){
    int u = 480 + (bid - 256);        // 480..499
    f32x4 acc[4] = {};
    gemm_slice(Al, Wl, Zb, 2560, 2048, fc_w + 2048, 2560, u*64, acc);
    gemm_slice(Al, Wl, Zb, 2560, 2304, fc_w + 2304, 2560, u*64, acc);
    tile_store(predP, 32000, u*64, acc, 1, nullptr, nullptr);
  }
  gridsync(cnt, gen);

  // ---------------- P4: gates0 (256) || fc ctx-segment (256) ----------------
  if (bid < 256){
    for (int u = bid; u < 640; u += 256){
      int sl = u >> 6, ct = u & 63;
      int k0 = sl*256;
      const float* Wb; int sW;
      if (k0 < 1536){ Wb = w_ih0 + k0; sW = 1536; }
      else          { Wb = w_hh0 + (k0 - 1536); sW = 1024; }
      f32x4 acc[4] = {};
      gemm_slice(Al, Wl, A0, 2560, k0, Wb, sW, ct*64, acc);
      tile_store(PbG + (long)sl*262144, 4096, ct*64, acc, 0, nullptr, nullptr);
    }
  } else {
    for (int u = bid - 256; u < 500; u += 256){
      f32x4 acc[4] = {};
      #pragma unroll
      for (int s = 4; s < 8; ++s)
        gemm_slice(Al, Wl, Zb, 2560, s*256, fc_w + s*256, 2560, u*64, acc);
      tile_store(predP, 32000, u*64, acc, 2, nullptr, nullptr);
    }
  }
  gridsync(cnt, gen);

  // ---------------- P5: lstm0 ----------------
  if (bid < 256){
    const int i = bid*256 + t;
    const int b = i >> 10, n = i & 1023;
    float g4[4];
    #pragma unroll
    for (int gi = 0; gi < 4; ++gi){
      int col = gi*1024 + n;
      float s = b_ih0[col] + b_hh0[col];
      const float* p = PbG + (long)b*4096 + col;
      for (int sl = 0; sl < 10; ++sl) s += p[(long)sl * 262144];
      g4[gi] = s;
    }
    float iv = fast_sig(g4[0]), fv = fast_sig(g4[1]);
    float gv = fast_tanh(g4[2]), ov = fast_sig(g4[3]);
    float c = fv * cell[i] + iv * gv;
    float h = ov * fast_tanh(c);
    nc[i] = c; nh[i] = h;
    A1[(long)b*2048 + n] = f2bf(h);
  }
  gridsync(cnt, gen);

  // ---------------- P6: gates1 (512 units) ----------------
  {
    int sl = bid >> 6, ct = bid & 63;
    int k0 = sl*256;
    const float* Wb; int sW;
    if (k0 < 1024){ Wb = w_ih1 + k0; sW = 1024; }
    else          { Wb = w_hh1 + (k0 - 1024); sW = 1024; }
    f32x4 acc[4] = {};
    gemm_slice(Al, Wl, A1, 2048, k0, Wb, sW, ct*64, acc);
    tile_store(PbG + (long)sl*262144, 4096, ct*64, acc, 0, nullptr, nullptr);
  }
  gridsync(cnt, gen);

  // ---------------- P7: lstm1 ----------------
  if (bid < 256){
    const int i = bid*256 + t;
    const int b = i >> 10, n = i & 1023;
    float g4[4];
    #pragma unroll
    for (int gi = 0; gi < 4; ++gi){
      int col = gi*1024 + n;
      float s = b_ih1[col] + b_hh1[col];
      const float* p = PbG + (long)b*4096 + col;
      for (int sl = 0; sl < 8; ++sl) s += p[(long)sl * 262144];
      g4[gi] = s;
    }
    float iv = fast_sig(g4[0]), fv = fast_sig(g4[1]);
    float gv = fast_tanh(g4[2]), ov = fast_sig(g4[3]);
    float c = fv * cell[65536 + i] + iv * gv;
    float h = ov * fast_tanh(c);
    nc[65536 + i] = c; nh[65536 + i] = h;
    Zb[(long)b*2560 + n] = f2bf(h);
  }
  gridsync(cnt, gen);

  // ---------------- P8: fc h1-segment + final sum ----------------
  if (bid < 500){
    f32x4 acc[4] = {};
    #pragma unroll
    for (int s = 0; s < 4; ++s)
      gemm_slice(Al, Wl, Zb, 2560, s*256, fc_w + s*256, 2560, bid*64, acc);
    tile_store(pred, 32000, bid*64, acc, 3, predP, fc_b);
  }
}

extern "C" void kernel_launch(void* const* d_in, const int* in_sizes, int n_in,
                              void* d_out, int out_size, void* d_ws, size_t ws_size,
                              hipStream_t stream)
{
  const int*   tok    = (const int*)  d_in[0];
  const float* hidden = (const float*)d_in[1];
  const float* cell   = (const float*)d_in[2];
  const float* enc    = (const float*)d_in[3];
  const int*   mask   = (const int*)  d_in[4];
  const float* emb    = (const float*)d_in[5];
  const float* attn_w = (const float*)d_in[6];
  const float* attn_b = (const float*)d_in[7];
  const float* v_w    = (const float*)d_in[8];
  const float* w_ih0  = (const float*)d_in[9];
  const float* w_hh0  = (const float*)d_in[10];
  const float* b_ih0  = (const float*)d_in[11];
  const float* b_hh0  = (const float*)d_in[12];
  const float* w_ih1  = (const float*)d_in[13];
  const float* w_hh1  = (const float*)d_in[14];
  const float* b_ih1  = (const float*)d_in[15];
  const float* b_hh1  = (const float*)d_in[16];
  const float* fc_w   = (const float*)d_in[17];
  const float* fc_b   = (const float*)d_in[18];

  float* out  = (float*)d_out;
  float* pred = out;                 // [64,32000]
  float* nh   = out + 2048000;       // [2,64,1024]
  float* nc   = out + 2179072;       // [2,64,1024]
  float* aw   = out + 2310144;       // [64,128]

  char*  wsb   = (char*)d_ws;
  short* encbf = (short*)(wsb + 0);          // 16,777,216 B
  short* Wbf   = (short*)(wsb + 16777216);   //  1,048,576 B
  short* A0    = (short*)(wsb + 17825792);   //    327,680 B
  short* A1    = (short*)(wsb + 18153472);   //    262,144 B
  short* Zb    = (short*)(wsb + 18415616);   //    327,680 B
  float* sco   = (float*)(wsb + 18743296);   //     32,768 B
  float* PbH   = (float*)(wsb + 18776064);   //    524,288 B (4 planes 64x512)
  float* predP = (float*)(wsb + 19300352);   //  8,192,000 B (64x32000)
  float* PbG   = (float*)(wsb + 27492352);   // 10,485,760 B (10 planes 64x4096)
  unsigned* bar = (unsigned*)(wsb + 37978112); // 8 B (cnt, gen)

  hipMemsetAsync(bar, 0, 8, stream);
  hipFuncSetAttribute((const void*)mega,
                      hipFuncAttributeMaxDynamicSharedMemorySize, 65536);

  mega<<<NBLK, 256, 65536, stream>>>(
      tok, emb, hidden, cell, enc, mask, attn_w, attn_b, v_w,
      w_ih0, w_hh0, b_ih0, b_hh0, w_ih1, w_hh1, b_ih1, b_hh1, fc_w, fc_b,
      encbf, Wbf, A0, A1, Zb, sco, PbH, predP, PbG, bar,
      pred, nh, nc, aw);
}

// Round 9
// 218.155 us; speedup vs baseline: 6.8907x; 6.8907x over previous
//
#include <hip/hip_runtime.h>

// Decoder step: embed -> additive attention -> 2-layer LSTM -> fc
// B=64, S=128, E=512, H=512, H2=1024, V=32000
// GEMMs: bf16 MFMA 16x16x32. A staged to LDS (XOR-swizzled via pre-swizzled
// global source), W streamed f32 via global_load_lds with counted vmcnt waits
// (never drained mid-loop). fc: 500 blocks x 4 waves, 80KB LDS = 2 blocks/CU,
// per-wave-private W streams, A double-buffered per 128-k chunk.

typedef __attribute__((ext_vector_type(8))) short bf16x8;
typedef __attribute__((ext_vector_type(4))) float f32x4;

__device__ __forceinline__ short f2bf(float f){
  __bf16 h = (__bf16)f;
  return __builtin_bit_cast(short, h);
}

__device__ __forceinline__ bf16x8 cvt8(float4 a, float4 b){
  bf16x8 r;
  r[0]=f2bf(a.x); r[1]=f2bf(a.y); r[2]=f2bf(a.z); r[3]=f2bf(a.w);
  r[4]=f2bf(b.x); r[5]=f2bf(b.y); r[6]=f2bf(b.z); r[7]=f2bf(b.w);
  return r;
}

__device__ __forceinline__ bf16x8 ld8_bf(const float* __restrict__ p){
  return cvt8(*(const float4*)p, *(const float4*)(p + 4));
}

__device__ __forceinline__ float fast_tanh(float x){
  x = fminf(fmaxf(x, -15.f), 15.f);
  float t = __expf(2.f * x);
  return (t - 1.f) / (t + 1.f);
}
__device__ __forceinline__ float fast_sig(float x){
  return 1.f / (1.f + __expf(-x));
}

__device__ __forceinline__ void stage16(const void* src, void* dst_lds){
  __builtin_amdgcn_global_load_lds(
      (const __attribute__((address_space(1))) void*)src,
      (__attribute__((address_space(3))) void*)dst_lds, 16, 0, 0);
}

// ---------------------------------------------------------------------------
// Fused prep: enc->bf16, attn_w[:,1024:2048]->bf16, emb gather, hidden cvt,
// scores zero.
// ---------------------------------------------------------------------------
__global__ __launch_bounds__(256) void prep_all(
    const int* __restrict__ tok, const float* __restrict__ emb,
    const float* __restrict__ hidden, const float* __restrict__ enc,
    const float* __restrict__ attn_w,
    short* __restrict__ encbf, short* __restrict__ Wbf,
    short* __restrict__ A0, short* __restrict__ A1, short* __restrict__ Zb,
    float* __restrict__ sco)
{
  const int bid = blockIdx.x, t = threadIdx.x;
  if (bid < 4096){
    long i = ((long)bid*256 + t)*8;
    *(bf16x8*)(encbf + i) = ld8_bf(enc + i);
  } else if (bid < 4352){
    int j = (bid-4096)*256 + t;
    int r = j >> 7, c = (j & 127)*8;
    *(bf16x8*)(Wbf + r*1024 + c) = ld8_bf(attn_w + (long)r*2048 + 1024 + c);
  } else if (bid < 4368){
    int j = (bid-4352)*256 + t;
    int b = j >> 6, e8 = (j & 63)*8;
    bf16x8 v = ld8_bf(emb + (long)tok[b]*512 + e8);
    *(bf16x8*)(A0 + b*2560 + e8) = v;
    *(bf16x8*)(Zb + b*2560 + 2048 + e8) = v;
  } else if (bid < 4400){
    int j = (bid-4368)*256 + t;
    int b = j >> 7, n8 = (j & 127)*8;
    *(bf16x8*)(A0 + b*2560 + 1536 + n8) = ld8_bf(hidden + (long)b*1024 + n8);
    *(bf16x8*)(A1 + b*2048 + 1024 + n8) = ld8_bf(hidden + 65536 + (long)b*1024 + n8);
  } else {
    int j = (bid-4400)*256 + t;
    float4 z = {0.f, 0.f, 0.f, 0.f};
    *(float4*)(sco + j*8) = z;
    *(float4*)(sco + j*8 + 4) = z;
  }
}

// ---------------------------------------------------------------------------
// P[by][64][N] = A_bf16[64,K] @ [W1|W2][N,:]^T on a 256-wide k-slice.
// (hproj + LSTM gates; split-K partials, consumer reduces)
// ---------------------------------------------------------------------------
#define KSL 256
__global__ __launch_bounds__(256) void gemm_lds(
    const short* __restrict__ A, int lda,
    const float* __restrict__ W1, int sW1, int K1,
    const float* __restrict__ W2, int sW2,
    float* __restrict__ P, int N)
{
  __shared__ short Al[64*256];     // 32 KB
  __shared__ float Wl[3][64*64];   // 48 KB
  const int wv   = threadIdx.x >> 6;
  const int lane = threadIdx.x & 63;
  const int l15  = lane & 15;
  const int lg   = lane >> 4;
  const int nb   = blockIdx.x * 64;
  const int k0   = blockIdx.y * KSL;

  const float* W; int sW, koff;
  if (k0 < K1){ W = W1; sW = sW1; koff = k0; }
  else        { W = W2; sW = sW2; koff = k0 - K1; }

  {
    const int r2  = lane >> 5;
    const int c16 = (lane & 31) * 16;
    #pragma unroll
    for (int i = 0; i < 8; ++i){
      int rbase = wv*16 + i*2;
      int row   = rbase + r2;
      const char* src = (const char*)A + (long)row*lda*2 + (long)k0*2
                        + (c16 ^ ((row & 7) << 4));
      stage16(src, (void*)(Al + rbase*256));
    }
  }

  auto STAGEW = [&](int bi, int kbase){
    #pragma unroll
    for (int i = 0; i < 4; ++i){
      int row = wv*16 + i*4 + lg;
      const char* src = (const char*)(W + (long)(nb + row)*sW + koff + kbase)
                        + ((l15*16) ^ ((row & 7) << 4));
      stage16(src, (void*)&Wl[bi][(wv*16 + i*4)*64]);
    }
  };

  STAGEW(0, 0);
  STAGEW(1, 64);
  asm volatile("s_waitcnt vmcnt(8)" ::: "memory");
  asm volatile("s_barrier" ::: "memory");

  f32x4 acc[4];
  #pragma unroll
  for (int m = 0; m < 4; ++m) acc[m] = (f32x4){0.f,0.f,0.f,0.f};

  const int  rl = wv*16 + l15;
  const int  sw = (l15 & 7) << 4;
  const char* wbase = (const char*)&Wl[0][0];
  const char* abase = (const char*)Al;

  auto COMPUTE = [&](int bi, int t){
    bf16x8 a[4][2];
    #pragma unroll
    for (int m = 0; m < 4; ++m)
      #pragma unroll
      for (int h = 0; h < 2; ++h){
        int cb = t*128 + h*64 + lg*16;
        a[m][h] = *(const bf16x8*)(abase + (m*16 + l15)*512 + (cb ^ sw));
      }
    const char* rb = wbase + bi*16384 + rl*256;
    float4 w00 = *(const float4*)(rb + ((lg*32      ) ^ sw));
    float4 w01 = *(const float4*)(rb + ((lg*32 + 16 ) ^ sw));
    float4 w10 = *(const float4*)(rb + ((lg*32 + 128) ^ sw));
    float4 w11 = *(const float4*)(rb + ((lg*32 + 144) ^ sw));
    bf16x8 wf0 = cvt8(w00, w01);
    bf16x8 wf1 = cvt8(w10, w11);
    #pragma unroll
    for (int m = 0; m < 4; ++m)
      acc[m] = __builtin_amdgcn_mfma_f32_16x16x32_bf16(a[m][0], wf0, acc[m], 0,0,0);
    #pragma unroll
    for (int m = 0; m < 4; ++m)
      acc[m] = __builtin_amdgcn_mfma_f32_16x16x32_bf16(a[m][1], wf1, acc[m], 0,0,0);
  };

  asm volatile("s_waitcnt vmcnt(4)" ::: "memory");
  COMPUTE(0, 0);
  STAGEW(2, 128);
  asm volatile("s_waitcnt vmcnt(4)" ::: "memory");
  COMPUTE(1, 1);
  STAGEW(0, 192);
  asm volatile("s_waitcnt vmcnt(4)" ::: "memory");
  COMPUTE(2, 2);
  asm volatile("s_waitcnt vmcnt(0)" ::: "memory");
  COMPUTE(0, 3);

  float* p = P + (long)blockIdx.y * 64 * N;
  #pragma unroll
  for (int mt = 0; mt < 4; ++mt)
    #pragma unroll
    for (int r = 0; r < 4; ++r){
      int m = mt*16 + lg*4 + r;
      p[(long)m * N + nb + wv*16 + l15] = acc[mt][r];
    }
}

// ---------------------------------------------------------------------------
// fc: C[64,N] = A[64,2560] @ W[N,2560]^T + bias. Full K, no split.
// 500 blocks x 256 threads (4 waves, 64 cols). LDS 80 KB -> 2 blocks/CU.
// W staging per-wave-private (16 rows/wave, no cross-wave dependency);
// A double-buffered per 128-k chunk (barrier per chunk, 4-wave).
// Counted vmcnt: steady in-flight 8-12 insts/wave, never drained to 0.
// ---------------------------------------------------------------------------
__global__ __launch_bounds__(256) void gemm_fc2(
    const short* __restrict__ A, int lda,
    const float* __restrict__ W, int sW,
    const float* __restrict__ bias,
    float* __restrict__ C, int N)
{
  __shared__ short Al[2][64*128];   // 2 x 16 KB
  __shared__ float Wl[3][64*64];    // 3 x 16 KB
  const int wv   = threadIdx.x >> 6;
  const int lane = threadIdx.x & 63;
  const int l15  = lane & 15;
  const int lg   = lane >> 4;
  const int nb   = blockIdx.x * 64;

  auto STAGEA = [&](int c){                 // 4 insts/wave, 16 rows/wave
    short* dst = Al[c & 1];
    #pragma unroll
    for (int i = 0; i < 4; ++i){
      int rbase = wv*16 + i*4;
      int row   = rbase + lg;
      const char* src = (const char*)(A + (long)row*lda + c*128)
                        + ((l15*16) ^ ((row & 7) << 4));
      stage16(src, (void*)(dst + rbase*128));
    }
  };
  auto STAGEW = [&](int s){                 // 4 insts/wave, own 16 rows
    float* dst = Wl[s % 3];
    #pragma unroll
    for (int i = 0; i < 4; ++i){
      int row = wv*16 + i*4 + lg;
      const char* src = (const char*)(W + (long)(nb + row)*sW + s*64)
                        + ((l15*16) ^ ((row & 7) << 4));
      stage16(src, (void*)(dst + (wv*16 + i*4)*64));
    }
  };

  f32x4 acc[4];
  #pragma unroll
  for (int m = 0; m < 4; ++m) acc[m] = (f32x4){0.f,0.f,0.f,0.f};

  const int rl = wv*16 + l15;
  const int sw = (l15 & 7) << 4;

  auto COMPUTE = [&](int s){
    const char* abase = (const char*)Al[(s >> 1) & 1];
    const int   kh    = (s & 1) * 128;
    bf16x8 a[4][2];
    #pragma unroll
    for (int m = 0; m < 4; ++m)
      #pragma unroll
      for (int h = 0; h < 2; ++h){
        int cb = kh + h*64 + lg*16;
        a[m][h] = *(const bf16x8*)(abase + (m*16 + l15)*256 + (cb ^ sw));
      }
    const char* rb = (const char*)Wl[s % 3] + rl*256;
    float4 w00 = *(const float4*)(rb + ((lg*32      ) ^ sw));
    float4 w01 = *(const float4*)(rb + ((lg*32 + 16 ) ^ sw));
    float4 w10 = *(const float4*)(rb + ((lg*32 + 128) ^ sw));
    float4 w11 = *(const float4*)(rb + ((lg*32 + 144) ^ sw));
    bf16x8 wf0 = cvt8(w00, w01);
    bf16x8 wf1 = cvt8(w10, w11);
    #pragma unroll
    for (int m = 0; m < 4; ++m)
      acc[m] = __builtin_amdgcn_mfma_f32_16x16x32_bf16(a[m][0], wf0, acc[m], 0,0,0);
    #pragma unroll
    for (int m = 0; m < 4; ++m)
      acc[m] = __builtin_amdgcn_mfma_f32_16x16x32_bf16(a[m][1], wf1, acc[m], 0,0,0);
  };

  // prologue: A(0), W(0), W(1); drain A0+W0 (W1 stays in flight)
  STAGEA(0); STAGEW(0); STAGEW(1);
  asm volatile("s_waitcnt vmcnt(4)" ::: "memory");
  __builtin_amdgcn_s_barrier();

  // chunk 0 (peeled: no vmcnt(8) needed before step 0)
  STAGEA(1);
  COMPUTE(0);
  STAGEW(2);
  asm volatile("s_waitcnt vmcnt(4)" ::: "memory");   // W1, A1 done
  COMPUTE(1);
  STAGEW(3);
  __builtin_amdgcn_s_barrier();

  for (int c = 1; c < 19; ++c){
    STAGEA(c+1);
    asm volatile("s_waitcnt vmcnt(8)" ::: "memory"); // W(2c) done
    COMPUTE(2*c);
    STAGEW(2*c+2);
    asm volatile("s_waitcnt vmcnt(4)" ::: "memory"); // W(2c+1), A(c+1) done
    COMPUTE(2*c+1);
    STAGEW(2*c+3);
    __builtin_amdgcn_s_barrier();
  }

  // chunk 19 (epilogue)
  asm volatile("s_waitcnt vmcnt(4)" ::: "memory");   // W(38) done
  COMPUTE(38);
  asm volatile("s_waitcnt vmcnt(0)" ::: "memory");   // W(39) done
  COMPUTE(39);

  const int col = nb + wv*16 + l15;
  const float bn = bias[col];
  #pragma unroll
  for (int mt = 0; mt < 4; ++mt)
    #pragma unroll
    for (int r = 0; r < 4; ++r){
      int m = mt*16 + lg*4 + r;
      C[(long)m * N + col] = acc[mt][r] + bn;
    }
}

// ---------------------------------------------------------------------------
// energy: T = encbf @ Wbf^T, scores[m] += v . tanh(T + hproj[b,n])
// hproj = sum of 4 split-K partials (Ph) + attn_b, folded inline.
// grid 1024: m3 = bx&127 (fast -> XCD id) for enc L2 reuse.
// ---------------------------------------------------------------------------
__global__ __launch_bounds__(256) void energy_k(
    const short* __restrict__ encbf, const short* __restrict__ Wbf,
    const float* __restrict__ Ph, const float* __restrict__ attn_b,
    const float* __restrict__ v_w, float* __restrict__ scores)
{
  const int bx = blockIdx.x;
  const int m3 = bx & 127, n3 = bx >> 7;
  const int wave = threadIdx.x >> 6;
  const int lane = threadIdx.x & 63;
  const int l15  = lane & 15;
  const int lg   = lane >> 4;
  const int mb   = m3 * 64;
  const int nb   = n3 * 64 + wave * 16;
  const int b    = mb >> 7;

  const int hi = b*512 + nb + l15;
  const float hp = attn_b[nb + l15] + Ph[hi] + Ph[32768 + hi]
                 + Ph[65536 + hi] + Ph[98304 + hi];

  f32x4 acc[4] = {};
  const short* ap  = encbf + (long)(mb + l15) * 1024 + lg * 8;
  const short* wpb = Wbf   + (long)(nb + l15) * 1024 + lg * 8;

  bf16x8 wn  = *(const bf16x8*)(wpb);
  bf16x8 an0 = *(const bf16x8*)(ap);
  bf16x8 an1 = *(const bf16x8*)(ap + 16*1024);
  bf16x8 an2 = *(const bf16x8*)(ap + 32*1024);
  bf16x8 an3 = *(const bf16x8*)(ap + 48*1024);
  for (int kb = 32; kb < 1024; kb += 32){
    bf16x8 wc = wn, c0 = an0, c1 = an1, c2 = an2, c3 = an3;
    wn  = *(const bf16x8*)(wpb + kb);
    an0 = *(const bf16x8*)(ap + kb);
    an1 = *(const bf16x8*)(ap + kb + 16*1024);
    an2 = *(const bf16x8*)(ap + kb + 32*1024);
    an3 = *(const bf16x8*)(ap + kb + 48*1024);
    acc[0] = __builtin_amdgcn_mfma_f32_16x16x32_bf16(c0, wc, acc[0], 0,0,0);
    acc[1] = __builtin_amdgcn_mfma_f32_16x16x32_bf16(c1, wc, acc[1], 0,0,0);
    acc[2] = __builtin_amdgcn_mfma_f32_16x16x32_bf16(c2, wc, acc[2], 0,0,0);
    acc[3] = __builtin_amdgcn_mfma_f32_16x16x32_bf16(c3, wc, acc[3], 0,0,0);
  }
  acc[0] = __builtin_amdgcn_mfma_f32_16x16x32_bf16(an0, wn, acc[0], 0,0,0);
  acc[1] = __builtin_amdgcn_mfma_f32_16x16x32_bf16(an1, wn, acc[1], 0,0,0);
  acc[2] = __builtin_amdgcn_mfma_f32_16x16x32_bf16(an2, wn, acc[2], 0,0,0);
  acc[3] = __builtin_amdgcn_mfma_f32_16x16x32_bf16(an3, wn, acc[3], 0,0,0);

  const float vn = v_w[nb + l15];
  #pragma unroll
  for (int mt = 0; mt < 4; ++mt){
    #pragma unroll
    for (int r = 0; r < 4; ++r){
      int m = mb + mt*16 + lg*4 + r;
      float e = fast_tanh(acc[mt][r] + hp) * vn;
      e += __shfl_xor(e, 1, 16);
      e += __shfl_xor(e, 2, 16);
      e += __shfl_xor(e, 4, 16);
      e += __shfl_xor(e, 8, 16);
      if (l15 == 0) atomicAdd(&scores[m], e);
    }
  }
}

// Fused masked softmax + context
__global__ __launch_bounds__(256) void ctxsm_k(
    const float* __restrict__ sco, const int* __restrict__ mask,
    const short* __restrict__ encbf, float* __restrict__ aw,
    short* __restrict__ A0, short* __restrict__ Zb)
{
  const int bb = blockIdx.x;
  const int t  = threadIdx.x;
  __shared__ float red[128];
  __shared__ float w[128];
  float v = 0.f;
  if (t < 128){
    v = sco[bb*128 + t];
    if (mask[bb*128 + t] == 0) v = -1e10f;
    red[t] = v;
  }
  __syncthreads();
  for (int d = 64; d > 0; d >>= 1){
    if (t < d) red[t] = fmaxf(red[t], red[t + d]);
    __syncthreads();
  }
  const float mx = red[0];
  __syncthreads();
  if (t < 128){
    float e = __expf(v - mx);
    w[t] = e; red[t] = e;
  }
  __syncthreads();
  for (int d = 64; d > 0; d >>= 1){
    if (t < d) red[t] += red[t + d];
    __syncthreads();
  }
  const float inv = 1.f / red[0];
  if (blockIdx.y == 0 && t < 128) aw[bb*128 + t] = w[t] * inv;

  const int dd = blockIdx.y * 256 + t;
  const unsigned short* e = (const unsigned short*)encbf + (long)bb*131072 + dd;
  float s = 0.f;
  #pragma unroll 4
  for (int si = 0; si < 128; ++si){
    float ev = __builtin_bit_cast(float, (unsigned)e[si*1024] << 16);
    s += w[si] * ev;
  }
  s *= inv;
  short vbf = f2bf(s);
  A0[bb*2560 + 512  + dd] = vbf;
  Zb[bb*2560 + 1024 + dd] = vbf;
}

// LSTM epilogue with fused split-K reduce
__global__ __launch_bounds__(256) void lstm_k(
    const float* __restrict__ P, int KS,
    const float* __restrict__ bi, const float* __restrict__ bh,
    const float* __restrict__ c_prev,
    float* __restrict__ h_out, float* __restrict__ c_out,
    short* __restrict__ h_bf, int bf_stride)
{
  const int i = blockIdx.x * 256 + threadIdx.x;
  const int b = i >> 10, n = i & 1023;
  float g4[4];
  #pragma unroll
  for (int gi = 0; gi < 4; ++gi){
    int col = gi*1024 + n;
    float s = bi[col] + bh[col];
    const float* p = P + (long)b*4096 + col;
    for (int sl = 0; sl < KS; ++sl) s += p[(long)sl * 262144];
    g4[gi] = s;
  }
  float iv = fast_sig (g4[0]);
  float fv = fast_sig (g4[1]);
  float gv = fast_tanh(g4[2]);
  float ov = fast_sig (g4[3]);
  float c = fv * c_prev[i] + iv * gv;
  float h = ov * fast_tanh(c);
  c_out[i] = c;
  h_out[i] = h;
  h_bf[(long)b * bf_stride + n] = f2bf(h);
}

extern "C" void kernel_launch(void* const* d_in, const int* in_sizes, int n_in,
                              void* d_out, int out_size, void* d_ws, size_t ws_size,
                              hipStream_t stream)
{
  const int*   tok    = (const int*)  d_in[0];
  const float* hidden = (const float*)d_in[1];
  const float* cell   = (const float*)d_in[2];
  const float* enc    = (const float*)d_in[3];
  const int*   mask   = (const int*)  d_in[4];
  const float* emb    = (const float*)d_in[5];
  const float* attn_w = (const float*)d_in[6];
  const float* attn_b = (const float*)d_in[7];
  const float* v_w    = (const float*)d_in[8];
  const float* w_ih0  = (const float*)d_in[9];
  const float* w_hh0  = (const float*)d_in[10];
  const float* b_ih0  = (const float*)d_in[11];
  const float* b_hh0  = (const float*)d_in[12];
  const float* w_ih1  = (const float*)d_in[13];
  const float* w_hh1  = (const float*)d_in[14];
  const float* b_ih1  = (const float*)d_in[15];
  const float* b_hh1  = (const float*)d_in[16];
  const float* fc_w   = (const float*)d_in[17];
  const float* fc_b   = (const float*)d_in[18];

  float* out  = (float*)d_out;
  float* pred = out;                 // [64,32000]
  float* nh   = out + 2048000;       // [2,64,1024]
  float* nc   = out + 2179072;       // [2,64,1024]
  float* aw   = out + 2310144;       // [64,128]

  char*  wsb   = (char*)d_ws;
  short* encbf = (short*)(wsb + 0);          // 16,777,216 B
  short* Wbf   = (short*)(wsb + 16777216);   //  1,048,576 B
  short* A0    = (short*)(wsb + 17825792);   //    327,680 B
  short* A1    = (short*)(wsb + 18153472);   //    262,144 B
  short* Zb    = (short*)(wsb + 18415616);   //    327,680 B
  float* sco   = (float*)(wsb + 18743296);   //     32,768 B
  float* Pb    = (float*)(wsb + 18776064);   // partials (hproj 4 / gates 10)

  prep_all<<<4404, 256, 0, stream>>>(tok, emb, hidden, enc, attn_w,
                                     encbf, Wbf, A0, A1, Zb, sco);

  // hproj partials = h_top @ attn_w[:,0:1024]^T  (4 x 256-k slices)
  gemm_lds<<<dim3(8, 4), 256, 0, stream>>>(A1 + 1024, 2048,
                                           attn_w, 2048, 1<<30, nullptr, 0,
                                           Pb, 512);

  energy_k<<<1024, 256, 0, stream>>>(encbf, Wbf, Pb, attn_b, v_w, sco);

  ctxsm_k<<<dim3(64, 4), 256, 0, stream>>>(sco, mask, encbf, aw, A0, Zb);

  // layer 0: A0 = [emb | ctx | h0_prev], W = [w_ih0 | w_hh0], K=2560
  gemm_lds<<<dim3(64, 10), 256, 0, stream>>>(A0, 2560,
                                             w_ih0, 1536, 1536, w_hh0, 1024,
                                             Pb, 4096);
  lstm_k<<<256, 256, 0, stream>>>(Pb, 10, b_ih0, b_hh0, cell,
                                  nh, nc, A1, 2048);

  // layer 1: A1 = [h0' | h1_prev], W = [w_ih1 | w_hh1], K=2048
  gemm_lds<<<dim3(64, 8), 256, 0, stream>>>(A1, 2048,
                                            w_ih1, 1024, 1024, w_hh1, 1024,
                                            Pb, 4096);
  lstm_k<<<256, 256, 0, stream>>>(Pb, 8, b_ih1, b_hh1, cell + 65536,
                                  nh + 65536, nc + 65536, Zb, 2560);

  // prediction = Zb @ fc_w^T + fc_b  (full-K, 2 blocks/CU)
  gemm_fc2<<<500, 256, 0, stream>>>(Zb, 2560, fc_w, 2560, fc_b, pred, 32000);
}